// Round 1
// baseline (511.147 us; speedup 1.0000x reference)
//
#include <hip/hip_runtime.h>
#include <hip/hip_bf16.h>
#include <math.h>

// Problem constants
#define B_   16
#define C_   64
#define H_   256
#define W_   256
#define CKK_ 576      // 64*3*3
#define FC_  512
#define ROWS 8        // output rows per wave in the conv kernel

// ---------------------------------------------------------------------------
// Kernel 1: MLP (Linear->ReLU->Linear) + softmax over 576, per batch sample.
// grid = B_ (16), block = CKK_ (576 = 9 waves)
// ---------------------------------------------------------------------------
__global__ __launch_bounds__(CKK_) void mlp_softmax_kernel(
    const float* __restrict__ F_c,   // [B,512]
    const float* __restrict__ W1,    // [512,576] row-major
    const float* __restrict__ b1,    // [576]
    const float* __restrict__ W2,    // [576,576]
    const float* __restrict__ b2,    // [576]
    float* __restrict__ kw_out)      // [B,576]
{
    const int b   = blockIdx.x;
    const int j   = threadIdx.x;     // 0..575
    const int lane = j & 63;
    const int wave = j >> 6;         // 0..8

    __shared__ float xs[FC_];
    __shared__ float hs[CKK_];
    __shared__ float red[12];

    if (j < FC_) xs[j] = F_c[b * FC_ + j];
    __syncthreads();

    // layer 1: h_j = relu(sum_i x_i * W1[i,j] + b1[j]); coalesced across j
    float acc = b1[j];
    #pragma unroll 8
    for (int i = 0; i < FC_; ++i)
        acc = fmaf(xs[i], W1[i * CKK_ + j], acc);
    hs[j] = fmaxf(acc, 0.0f);
    __syncthreads();

    // layer 2 logits
    float lg = b2[j];
    #pragma unroll 8
    for (int i = 0; i < CKK_; ++i)
        lg = fmaf(hs[i], W2[i * CKK_ + j], lg);

    // softmax over the 576 threads: max
    float m = lg;
    #pragma unroll
    for (int off = 32; off > 0; off >>= 1)
        m = fmaxf(m, __shfl_xor(m, off));
    if (lane == 0) red[wave] = m;
    __syncthreads();
    if (j == 0) {
        float mm = red[0];
        for (int i = 1; i < 9; ++i) mm = fmaxf(mm, red[i]);
        red[9] = mm;
    }
    __syncthreads();
    const float mm = red[9];

    const float e = expf(lg - mm);
    float s = e;
    #pragma unroll
    for (int off = 32; off > 0; off >>= 1)
        s += __shfl_xor(s, off);
    if (lane == 0) red[wave] = s;
    __syncthreads();
    if (j == 0) {
        float ss = 0.0f;
        for (int i = 0; i < 9; ++i) ss += red[i];
        red[10] = ss;
    }
    __syncthreads();

    kw_out[b * CKK_ + j] = e / red[10];
}

// ---------------------------------------------------------------------------
// Kernel 2: depthwise 3x3 conv with reflect padding.
// One wave = 8 output rows x 256 cols of one (b,c) plane; lane handles 4 cols.
// block = 256 (4 waves -> 32 rows), grid = B*C * (256/32) = 8192.
// ---------------------------------------------------------------------------
__device__ __forceinline__ void load_row6(const float* __restrict__ row,
                                          int x0, float v[6])
{
    const float4 c = *(const float4*)(row + x0);
    v[1] = c.x; v[2] = c.y; v[3] = c.z; v[4] = c.w;
    v[0] = (x0 == 0)        ? row[1]      : row[x0 - 1];
    v[5] = (x0 == W_ - 4)   ? row[W_ - 2] : row[x0 + 4];
}

__global__ __launch_bounds__(256) void dwconv_kernel(
    const float* __restrict__ in,    // [B*C,256,256]
    const float* __restrict__ kw,    // [B*C,9]
    float* __restrict__ out)         // [B*C,256,256]
{
    const int tid  = threadIdx.x;
    const int lane = tid & 63;
    const int wave = tid >> 6;

    const int tilesPerBC = H_ / (ROWS * 4);          // 8
    const int bc   = blockIdx.x / tilesPerBC;
    const int tile = blockIdx.x % tilesPerBC;
    const int y0   = tile * (ROWS * 4) + wave * ROWS;
    const int x0   = lane * 4;

    const float* base  = in  + (size_t)bc * H_ * W_;
    float*       obase = out + (size_t)bc * H_ * W_;

    const float* w = kw + bc * 9;
    const float w0 = w[0], w1 = w[1], w2 = w[2];
    const float w3 = w[3], w4 = w[4], w5 = w[5];
    const float w6 = w[6], w7 = w[7], w8 = w[8];

    float a[6], bb[6], c[6];
    const int ym = (y0 == 0) ? 1 : y0 - 1;           // reflect row -1 -> 1
    load_row6(base + (size_t)ym * W_, x0, a);
    load_row6(base + (size_t)y0 * W_, x0, bb);

    #pragma unroll
    for (int r = 0; r < ROWS; ++r) {
        int yn = y0 + r + 1;
        if (yn == H_) yn = H_ - 2;                   // reflect row 256 -> 254
        load_row6(base + (size_t)yn * W_, x0, c);

        float4 o;
        o.x = fmaf(a[0], w0, fmaf(a[1], w1, fmaf(a[2], w2,
              fmaf(bb[0], w3, fmaf(bb[1], w4, fmaf(bb[2], w5,
              fmaf(c[0], w6, fmaf(c[1], w7, c[2] * w8))))))));
        o.y = fmaf(a[1], w0, fmaf(a[2], w1, fmaf(a[3], w2,
              fmaf(bb[1], w3, fmaf(bb[2], w4, fmaf(bb[3], w5,
              fmaf(c[1], w6, fmaf(c[2], w7, c[3] * w8))))))));
        o.z = fmaf(a[2], w0, fmaf(a[3], w1, fmaf(a[4], w2,
              fmaf(bb[2], w3, fmaf(bb[3], w4, fmaf(bb[4], w5,
              fmaf(c[2], w6, fmaf(c[3], w7, c[4] * w8))))))));
        o.w = fmaf(a[3], w0, fmaf(a[4], w1, fmaf(a[5], w2,
              fmaf(bb[3], w3, fmaf(bb[4], w4, fmaf(bb[5], w5,
              fmaf(c[3], w6, fmaf(c[4], w7, c[5] * w8))))))));

        *(float4*)(obase + (size_t)(y0 + r) * W_ + x0) = o;

        #pragma unroll
        for (int i = 0; i < 6; ++i) { a[i] = bb[i]; bb[i] = c[i]; }
    }
}

// ---------------------------------------------------------------------------
extern "C" void kernel_launch(void* const* d_in, const int* in_sizes, int n_in,
                              void* d_out, int out_size, void* d_ws, size_t ws_size,
                              hipStream_t stream)
{
    const float* F_d = (const float*)d_in[0];
    const float* F_c = (const float*)d_in[1];
    const float* W1  = (const float*)d_in[2];
    const float* b1  = (const float*)d_in[3];
    const float* W2  = (const float*)d_in[4];
    const float* b2  = (const float*)d_in[5];

    float* out = (float*)d_out;
    float* kw  = out + (size_t)B_ * C_ * H_ * W_;   // kernel_weights output slot

    // 1) generate kernels
    mlp_softmax_kernel<<<B_, CKK_, 0, stream>>>(F_c, W1, b1, W2, b2, kw);

    // 2) depthwise conv (reads kw from d_out tail)
    const int tilesPerBC = H_ / (ROWS * 4);         // 8
    dwconv_kernel<<<B_ * C_ * tilesPerBC, 256, 0, stream>>>(F_d, kw, out);
}

// Round 2
// 466.260 us; speedup vs baseline: 1.0963x; 1.0963x over previous
//
#include <hip/hip_runtime.h>
#include <hip/hip_bf16.h>
#include <math.h>

// Problem constants
#define B_   16
#define C_   64
#define H_   256
#define W_   256
#define CKK_ 576      // 64*3*3
#define FC_  512
#define ROWS 16       // output rows per wave in the conv kernel

// ---------------------------------------------------------------------------
// Kernel A: layer1  h = relu(F_c @ W1 + b1)
// grid = B*9 blocks, block = 256 (4 waves). Each block computes 64 outputs of
// one sample; the 512-deep dot product is split 4 ways across waves.
// ---------------------------------------------------------------------------
__global__ __launch_bounds__(256) void mlp_layer1_kernel(
    const float* __restrict__ F_c,   // [B,512]
    const float* __restrict__ W1,    // [512,576]
    const float* __restrict__ b1,    // [576]
    float* __restrict__ h_out)       // [B,576] (in ws)
{
    const int b  = blockIdx.x / 9;
    const int jg = blockIdx.x % 9;
    const int jl = threadIdx.x & 63;
    const int p  = threadIdx.x >> 6;      // 0..3, K-chunk
    const int j  = jg * 64 + jl;

    __shared__ float xs[FC_];
    __shared__ float partial[256];

    xs[threadIdx.x]       = F_c[b * FC_ + threadIdx.x];
    xs[threadIdx.x + 256] = F_c[b * FC_ + threadIdx.x + 256];
    __syncthreads();

    const int i0 = p * 128;
    const float* wp = W1 + (size_t)i0 * CKK_ + j;
    float acc = 0.0f;
    #pragma unroll 8
    for (int i = 0; i < 128; ++i)
        acc = fmaf(xs[i0 + i], wp[(size_t)i * CKK_], acc);
    partial[threadIdx.x] = acc;
    __syncthreads();

    if (threadIdx.x < 64) {
        float s = partial[jl] + partial[64 + jl] + partial[128 + jl] + partial[192 + jl];
        h_out[b * CKK_ + j] = fmaxf(s + b1[j], 0.0f);
    }
}

// ---------------------------------------------------------------------------
// Kernel B: layer2 logits = h @ W2 + b2   (same structure, K=576 -> 4x144)
// ---------------------------------------------------------------------------
__global__ __launch_bounds__(256) void mlp_layer2_kernel(
    const float* __restrict__ h,     // [B,576] (ws)
    const float* __restrict__ W2,    // [576,576]
    const float* __restrict__ b2,    // [576]
    float* __restrict__ logits)      // [B,576] (ws)
{
    const int b  = blockIdx.x / 9;
    const int jg = blockIdx.x % 9;
    const int jl = threadIdx.x & 63;
    const int p  = threadIdx.x >> 6;
    const int j  = jg * 64 + jl;

    __shared__ float xs[CKK_];
    __shared__ float partial[256];

    xs[threadIdx.x]       = h[b * CKK_ + threadIdx.x];
    xs[threadIdx.x + 256] = h[b * CKK_ + threadIdx.x + 256];
    if (threadIdx.x < CKK_ - 512)
        xs[threadIdx.x + 512] = h[b * CKK_ + threadIdx.x + 512];
    __syncthreads();

    const int i0 = p * 144;
    const float* wp = W2 + (size_t)i0 * CKK_ + j;
    float acc = 0.0f;
    #pragma unroll 8
    for (int i = 0; i < 144; ++i)
        acc = fmaf(xs[i0 + i], wp[(size_t)i * CKK_], acc);
    partial[threadIdx.x] = acc;
    __syncthreads();

    if (threadIdx.x < 64) {
        float s = partial[jl] + partial[64 + jl] + partial[128 + jl] + partial[192 + jl];
        logits[b * CKK_ + j] = s + b2[j];
    }
}

// ---------------------------------------------------------------------------
// Kernel C: softmax over 576 logits per sample. grid = B, block = 576.
// ---------------------------------------------------------------------------
__global__ __launch_bounds__(CKK_) void softmax_kernel(
    const float* __restrict__ logits,  // [B,576] (ws)
    float* __restrict__ kw_out)        // [B,576] (d_out tail)
{
    const int b    = blockIdx.x;
    const int j    = threadIdx.x;
    const int lane = j & 63;
    const int wave = j >> 6;

    __shared__ float red[12];

    const float lg = logits[b * CKK_ + j];

    float m = lg;
    #pragma unroll
    for (int off = 32; off > 0; off >>= 1)
        m = fmaxf(m, __shfl_xor(m, off));
    if (lane == 0) red[wave] = m;
    __syncthreads();
    if (j == 0) {
        float mm = red[0];
        for (int i = 1; i < 9; ++i) mm = fmaxf(mm, red[i]);
        red[9] = mm;
    }
    __syncthreads();
    const float mm = red[9];

    const float e = expf(lg - mm);
    float s = e;
    #pragma unroll
    for (int off = 32; off > 0; off >>= 1)
        s += __shfl_xor(s, off);
    if (lane == 0) red[wave] = s;
    __syncthreads();
    if (j == 0) {
        float ss = 0.0f;
        for (int i = 0; i < 9; ++i) ss += red[i];
        red[10] = ss;
    }
    __syncthreads();

    kw_out[b * CKK_ + j] = e / red[10];
}

// ---------------------------------------------------------------------------
// Kernel D: depthwise 3x3 conv with reflect padding.
// One wave = 16 output rows x 256 cols; halo columns come from lane shuffles
// (1 VMEM load per row instead of 3). block = 256 (4 waves -> 64 rows),
// grid = B*C*(H/64) = 4096.
// ---------------------------------------------------------------------------
__device__ __forceinline__ void load_row_shfl(const float* __restrict__ row,
                                              int lane, float v[6])
{
    const float4 c = *(const float4*)(row + lane * 4);
    const float left  = __shfl_up(c.w, 1);    // row[x0-1] from lane-1
    const float right = __shfl_down(c.x, 1);  // row[x0+4] from lane+1
    v[0] = (lane == 0)  ? c.y : left;         // reflect col -1  -> col 1
    v[5] = (lane == 63) ? c.z : right;        // reflect col 256 -> col 254
    v[1] = c.x; v[2] = c.y; v[3] = c.z; v[4] = c.w;
}

__global__ __launch_bounds__(256) void dwconv_kernel(
    const float* __restrict__ in,    // [B*C,256,256]
    const float* __restrict__ kw,    // [B*C,9]
    float* __restrict__ out)         // [B*C,256,256]
{
    const int tid  = threadIdx.x;
    const int lane = tid & 63;
    const int wave = tid >> 6;

    const int tilesPerBC = H_ / (ROWS * 4);          // 4
    const int bc   = blockIdx.x / tilesPerBC;
    const int tile = blockIdx.x % tilesPerBC;
    const int y0   = tile * (ROWS * 4) + wave * ROWS;
    const int x0   = lane * 4;

    const float* base  = in  + (size_t)bc * H_ * W_;
    float*       obase = out + (size_t)bc * H_ * W_;

    const float* w = kw + bc * 9;
    const float w0 = w[0], w1 = w[1], w2 = w[2];
    const float w3 = w[3], w4 = w[4], w5 = w[5];
    const float w6 = w[6], w7 = w[7], w8 = w[8];

    float a[6], bb[6], c[6];
    const int ym = (y0 == 0) ? 1 : y0 - 1;           // reflect row -1 -> 1
    load_row_shfl(base + (size_t)ym * W_, lane, a);
    load_row_shfl(base + (size_t)y0 * W_, lane, bb);

    #pragma unroll
    for (int r = 0; r < ROWS; ++r) {
        int yn = y0 + r + 1;
        if (yn == H_) yn = H_ - 2;                   // reflect row 256 -> 254
        load_row_shfl(base + (size_t)yn * W_, lane, c);

        float4 o;
        o.x = fmaf(a[0], w0, fmaf(a[1], w1, fmaf(a[2], w2,
              fmaf(bb[0], w3, fmaf(bb[1], w4, fmaf(bb[2], w5,
              fmaf(c[0], w6, fmaf(c[1], w7, c[2] * w8))))))));
        o.y = fmaf(a[1], w0, fmaf(a[2], w1, fmaf(a[3], w2,
              fmaf(bb[1], w3, fmaf(bb[2], w4, fmaf(bb[3], w5,
              fmaf(c[1], w6, fmaf(c[2], w7, c[3] * w8))))))));
        o.z = fmaf(a[2], w0, fmaf(a[3], w1, fmaf(a[4], w2,
              fmaf(bb[2], w3, fmaf(bb[3], w4, fmaf(bb[4], w5,
              fmaf(c[2], w6, fmaf(c[3], w7, c[4] * w8))))))));
        o.w = fmaf(a[3], w0, fmaf(a[4], w1, fmaf(a[5], w2,
              fmaf(bb[3], w3, fmaf(bb[4], w4, fmaf(bb[5], w5,
              fmaf(c[3], w6, fmaf(c[4], w7, c[5] * w8))))))));

        *(float4*)(obase + (size_t)(y0 + r) * W_ + x0) = o;

        #pragma unroll
        for (int i = 0; i < 6; ++i) { a[i] = bb[i]; bb[i] = c[i]; }
    }
}

// ---------------------------------------------------------------------------
extern "C" void kernel_launch(void* const* d_in, const int* in_sizes, int n_in,
                              void* d_out, int out_size, void* d_ws, size_t ws_size,
                              hipStream_t stream)
{
    const float* F_d = (const float*)d_in[0];
    const float* F_c = (const float*)d_in[1];
    const float* W1  = (const float*)d_in[2];
    const float* b1  = (const float*)d_in[3];
    const float* W2  = (const float*)d_in[4];
    const float* b2  = (const float*)d_in[5];

    float* out    = (float*)d_out;
    float* kw     = out + (size_t)B_ * C_ * H_ * W_;  // kernel_weights output slot
    float* h_ws   = (float*)d_ws;                     // [B,576]
    float* lg_ws  = h_ws + B_ * CKK_;                 // [B,576]

    mlp_layer1_kernel<<<B_ * 9, 256, 0, stream>>>(F_c, W1, b1, h_ws);
    mlp_layer2_kernel<<<B_ * 9, 256, 0, stream>>>(h_ws, W2, b2, lg_ws);
    softmax_kernel<<<B_, CKK_, 0, stream>>>(lg_ws, kw);

    const int tilesPerBC = H_ / (ROWS * 4);           // 4
    dwconv_kernel<<<B_ * C_ * tilesPerBC, 256, 0, stream>>>(F_d, kw, out);
}